// Round 6
// baseline (284.948 us; speedup 1.0000x reference)
//
#include <hip/hip_runtime.h>

// Problem constants
#define B_ 2048
#define S_ 512
#define I_ 256
#define F_ 256
#define NG 8   // partial-groups for the W2 fold

// Workspace layout (in floats)
#define OFF_W    0                       // w[B,F]   (hidden @ W1^T)
#define OFF_SW   (OFF_W + B_*F_)         // Sw[B]    (row sums of w)
#define OFF_U    (OFF_SW + B_)           // u[B,S]
#define OFF_P    (OFF_U + B_*S_)         // p[B,S]
#define OFF_RP   (OFF_P + B_*S_)         // rp[NG][512] partial r = Wfc@W2
// total floats = OFF_RP + NG*512 = 2,628,608 (~10.5 MB)

// ---------------------------------------------------------------------------
// k_pre: blocks 0..511  : w[b,f] = hidden[b,:].W1[f,:], Sw[b] (4 batches/block)
//        blocks 512..519: partial fold rp[g][j] = sum_{i in g's 32} Wfc[i]*W2[i,j]
// (unchanged from R5)
__global__ __launch_bounds__(256) void k_pre(
    const float* __restrict__ hidden, const float* __restrict__ W1,
    const float* __restrict__ W2, const float* __restrict__ Wfc,
    float* __restrict__ ws) {
  const int tid = threadIdx.x;

  if (blockIdx.x >= B_ / 4) {
    const int g = blockIdx.x - B_ / 4;
    float acc0 = 0.f, acc1 = 0.f;
#pragma unroll 8
    for (int ii = 0; ii < 32; ++ii) {
      const int i = g * 32 + ii;
      const float f = Wfc[i];
      acc0 += f * W2[(size_t)i * (I_ + F_) + tid];
      acc1 += f * W2[(size_t)i * (I_ + F_) + tid + 256];
    }
    ws[OFF_RP + g * 512 + tid] = acc0;        // r_h partial
    ws[OFF_RP + g * 512 + 256 + tid] = acc1;  // r_v partial
    return;
  }

  __shared__ float h[4][I_];
  __shared__ float red[256];
  const int b0 = blockIdx.x * 4;
#pragma unroll
  for (int k = 0; k < 4; ++k) h[k][tid] = hidden[(size_t)(b0 + k) * I_ + tid];
  __syncthreads();

  const int f = tid;
  const float4* wrow = (const float4*)(W1 + (size_t)f * I_);
  float acc[4] = {0.f, 0.f, 0.f, 0.f};
#pragma unroll 4
  for (int iq = 0; iq < I_ / 4; ++iq) {
    const float4 v = wrow[iq];
    const int i = 4 * iq;
#pragma unroll
    for (int k = 0; k < 4; ++k)
      acc[k] += v.x * h[k][i] + v.y * h[k][i + 1] + v.z * h[k][i + 2] + v.w * h[k][i + 3];
  }
#pragma unroll
  for (int k = 0; k < 4; ++k) ws[OFF_W + (size_t)(b0 + k) * F_ + f] = acc[k];

#pragma unroll
  for (int k = 0; k < 4; ++k) {
    red[tid] = acc[k];
    __syncthreads();
    for (int s = 128; s > 0; s >>= 1) { if (tid < s) red[tid] += red[tid + s]; __syncthreads(); }
    if (tid == 0) ws[OFF_SW + b0 + k] = red[0];
    __syncthreads();
  }
}

// ---------------------------------------------------------------------------
// K1: single pass over inp (1 GB) — unchanged from R5.
__global__ __launch_bounds__(256) void k1_scan(
    const float* __restrict__ inp, const float* __restrict__ wsw,
    const float* __restrict__ wsrp,
    float* __restrict__ wsu, float* __restrict__ wsp) {
  const int ROWS = 32;
  const int b = blockIdx.y;
  const int t0 = blockIdx.x * ROWS;
  const int tid = threadIdx.x;
  const int lane = tid & 63;
  const int wid = tid >> 6;

  __shared__ float rv_lds[F_];
  float rv = 0.f;
#pragma unroll
  for (int g = 0; g < NG; ++g) rv += wsrp[g * 512 + 256 + tid];
  rv_lds[tid] = rv;
  __syncthreads();

  const float4 w4  = ((const float4*)(wsw + (size_t)b * F_))[lane];
  const float4 rv4 = ((const float4*)rv_lds)[lane];
  const float* base = inp + ((size_t)b * S_ + t0) * I_;
  float* uo = wsu + (size_t)b * S_ + t0;
  float* po = wsp + (size_t)b * S_ + t0;

#pragma unroll
  for (int rr = 0; rr < ROWS / 4; ++rr) {
    const int row = wid + 4 * rr;
    const float4 in4 = ((const float4*)(base + (size_t)row * I_))[lane];
    float du = in4.x * w4.x + in4.y * w4.y + in4.z * w4.z + in4.w * w4.w;
    float dp = in4.x * rv4.x + in4.y * rv4.y + in4.z * rv4.z + in4.w * rv4.w;
#pragma unroll
    for (int m = 32; m >= 1; m >>= 1) {
      du += __shfl_xor(du, m, 64);
      dp += __shfl_xor(dp, m, 64);
    }
    if (lane == 0) { uo[row] = du; po[row] = dp; }
  }
}

// ---------------------------------------------------------------------------
// K2 v2: register-tiled epilogue. 256 blocks, 8 batches/block.
// Thread (tk = tid&7 -> batch, txg = tid>>3 -> x = txg*8 + j, j<8).
// Per t-quad: 2 ds_read_b128 (u,p) + 8 Wc float4 (L2) + 64 FMA -> VALU-bound.
// u/p LDS padded [8][516]: batch-chunk k at banks 4k..4k+3 -> conflict-free.
__global__ __launch_bounds__(256) void k2_epilogue(
    const float* __restrict__ Wc, const float* __restrict__ bc,
    const float* __restrict__ b2, const float* __restrict__ Wfc,
    const float* __restrict__ bfc, const float* __restrict__ hidden,
    const float* __restrict__ wsu, const float* __restrict__ wsp,
    const float* __restrict__ wsSw, const float* __restrict__ wsrp,
    float* __restrict__ out) {
  const int b0 = blockIdx.x * 8;
  const int tid = threadIdx.x;
  const int tk  = tid & 7;
  const int txg = tid >> 3;
  const int lane = tid & 63;
  const int wid = tid >> 6;

  __shared__ float u_lds[8][516];
  __shared__ float p_lds[8][516];
  __shared__ float rh_lds[256];
  __shared__ float redA[4], redB[4];
  __shared__ float wred[4][8];

  // fold r partials for x = tid
  float rh = 0.f, rv = 0.f;
#pragma unroll
  for (int g = 0; g < NG; ++g) {
    rh += wsrp[g * 512 + tid];
    rv += wsrp[g * 512 + 256 + tid];
  }
  rh_lds[tid] = rh;

  // R = sum(r_v); c0 = Wfc.b2 + bfc
  float t0r = rv, t1r = Wfc[tid] * b2[tid];
#pragma unroll
  for (int m = 32; m >= 1; m >>= 1) {
    t0r += __shfl_xor(t0r, m, 64);
    t1r += __shfl_xor(t1r, m, 64);
  }
  if (lane == 0) { redA[wid] = t0r; redB[wid] = t1r; }

  // stage u,p for 8 batches (coalesced)
  for (int idx = tid; idx < 8 * S_; idx += 256) {
    const int k = idx >> 9, t = idx & (S_ - 1);
    u_lds[k][t] = wsu[(size_t)(b0 + k) * S_ + t];
    p_lds[k][t] = wsp[(size_t)(b0 + k) * S_ + t];
  }
  __syncthreads();

  const float R  = redA[0] + redA[1] + redA[2] + redA[3];
  const float c0 = redB[0] + redB[1] + redB[2] + redB[3] + bfc[0];

  float ss[8] = {0.f,0.f,0.f,0.f,0.f,0.f,0.f,0.f};
  float qs[8] = {0.f,0.f,0.f,0.f,0.f,0.f,0.f,0.f};
  const float* wcbase = Wc + (size_t)txg * 8 * S_;

#pragma unroll 2
  for (int t = 0; t < S_; t += 4) {
    const float4 u4 = *(const float4*)&u_lds[tk][t];
    const float4 p4 = *(const float4*)&p_lds[tk][t];
#pragma unroll
    for (int j = 0; j < 8; ++j) {
      const float4 w4 = *(const float4*)(wcbase + (size_t)j * S_ + t);
      ss[j] += w4.x * u4.x + w4.y * u4.y + w4.z * u4.z + w4.w * u4.w;
      qs[j] += w4.x * p4.x + w4.y * p4.y + w4.z * p4.z + w4.w * p4.w;
    }
  }

  // epilogue: s -> sigmoid -> contribution; + rh.hidden term
  const float Sw = wsSw[b0 + tk];
  const float4 bca = *(const float4*)(bc + txg * 8);
  const float4 bcb = *(const float4*)(bc + txg * 8 + 4);
  const float4 hda = *(const float4*)(hidden + (size_t)(b0 + tk) * I_ + txg * 8);
  const float4 hdb = *(const float4*)(hidden + (size_t)(b0 + tk) * I_ + txg * 8 + 4);
  const float bcv[8] = {bca.x, bca.y, bca.z, bca.w, bcb.x, bcb.y, bcb.z, bcb.w};
  const float hdv[8] = {hda.x, hda.y, hda.z, hda.w, hdb.x, hdb.y, hdb.z, hdb.w};

  float tot = 0.f;
#pragma unroll
  for (int j = 0; j < 8; ++j) {
    const float s = ss[j] + bcv[j] * Sw;
    const float a = 1.f / (1.f + expf(-s));
    tot += a * (qs[j] + bcv[j] * R) + rh_lds[txg * 8 + j] * hdv[j];
  }
  // reduce over txg within wave (tid bits 3,4,5)
  tot += __shfl_xor(tot, 8, 64);
  tot += __shfl_xor(tot, 16, 64);
  tot += __shfl_xor(tot, 32, 64);
  if (lane < 8) wred[wid][lane] = tot;   // lane == tk here
  __syncthreads();
  if (tid < 8)
    out[b0 + tid] = wred[0][tid] + wred[1][tid] + wred[2][tid] + wred[3][tid] + c0;
}

// ---------------------------------------------------------------------------
extern "C" void kernel_launch(void* const* d_in, const int* in_sizes, int n_in,
                              void* d_out, int out_size, void* d_ws, size_t ws_size,
                              hipStream_t stream) {
  (void)in_sizes; (void)n_in; (void)out_size; (void)ws_size;
  const float* hidden = (const float*)d_in[0];
  const float* inp    = (const float*)d_in[1];
  const float* W1     = (const float*)d_in[2];
  const float* Wc     = (const float*)d_in[3];
  const float* bc     = (const float*)d_in[4];
  const float* W2     = (const float*)d_in[5];
  const float* b2     = (const float*)d_in[6];
  const float* Wfc    = (const float*)d_in[7];
  const float* bfc    = (const float*)d_in[8];
  float* out = (float*)d_out;
  float* ws  = (float*)d_ws;

  hipLaunchKernelGGL(k_pre, dim3(B_ / 4 + NG), dim3(256), 0, stream,
                     hidden, W1, W2, Wfc, ws);
  hipLaunchKernelGGL(k1_scan, dim3(S_ / 32, B_), dim3(256), 0, stream,
                     inp, ws + OFF_W, ws + OFF_RP, ws + OFF_U, ws + OFF_P);
  hipLaunchKernelGGL(k2_epilogue, dim3(B_ / 8), dim3(256), 0, stream,
                     Wc, bc, b2, Wfc, bfc, hidden,
                     ws + OFF_U, ws + OFF_P, ws + OFF_SW, ws + OFF_RP, out);
}